// Round 1
// baseline (2242.912 us; speedup 1.0000x reference)
//
#include <hip/hip_runtime.h>
#include <hip/hip_bf16.h>
#include <math.h>

#define NN   100000   // nodes
#define DD   202      // feature dim
#define ET   6        // edge types
#define MM   200000   // edges per type
#define NPOS 512
#define DE   1212     // DD*ET
#define KK   202      // GEMM K

// ---------------- pos_gating: (512 x 202) = 2*sigmoid(pos_embs @ W_pos + b_pos)
__global__ void gating_kernel(const float* __restrict__ W_pos,
                              const float* __restrict__ b_pos,
                              float* __restrict__ gating) {
    int p = blockIdx.x;            // position 0..511
    __shared__ float emb[DD];
    int t = threadIdx.x;
    if (t < 100) {
        // inv_freq[j] = 10000^(-j/100)
        float invf = expf(-((float)t / 100.0f) * 9.210340371976184f); // ln(10000)
        float si = (float)p * invf;
        emb[t]       = sinf(si);
        emb[100 + t] = cosf(si);
    } else if (t < 102) {
        emb[100 + t] = 0.0f;       // pad dims 200,201
    }
    __syncthreads();
    if (t < DD) {
        float acc = b_pos[t];
        for (int k = 0; k < DD; ++k) acc += emb[k] * W_pos[k * DD + t];
        gating[p * DD + t] = 2.0f / (1.0f + expf(-acc));
    }
}

// ---------------- prop = node_states(100000x202) @ W_transform(202x1212) + b  -> bf16
// 128x128 tile, BK=16, 8x8 per thread, 256 threads
__global__ __launch_bounds__(256) void gemm_kernel(const float* __restrict__ A,
                                                   const float* __restrict__ B,
                                                   const float* __restrict__ bias,
                                                   __hip_bfloat16* __restrict__ C) {
    __shared__ float As[16 * 128];   // [k][m]
    __shared__ float Bs[16 * 128];   // [k][n]
    int t  = threadIdx.x;
    int tx = t & 15, ty = t >> 4;
    int col0 = blockIdx.x * 128;
    int row0 = blockIdx.y * 128;

    float acc[8][8];
    #pragma unroll
    for (int i = 0; i < 8; ++i)
        #pragma unroll
        for (int j = 0; j < 8; ++j) acc[i][j] = 0.0f;

    int am = t >> 1, ak = (t & 1) * 8;   // A loader: row am, k-offset ak
    int bk = t >> 4, bc = (t & 15) * 8;  // B loader: k-row bk, col-offset bc
    int arow = row0 + am;

    for (int kc = 0; kc < KK; kc += 16) {
        #pragma unroll
        for (int i = 0; i < 8; ++i) {
            int k = kc + ak + i;
            float v = (arow < NN && k < KK) ? A[(size_t)arow * KK + k] : 0.0f;
            As[(ak + i) * 128 + am] = v;
        }
        {
            int k = kc + bk;
            #pragma unroll
            for (int i = 0; i < 8; ++i) {
                int c = col0 + bc + i;
                float v = (k < KK && c < DE) ? B[(size_t)k * DE + c] : 0.0f;
                Bs[bk * 128 + bc + i] = v;
            }
        }
        __syncthreads();
        #pragma unroll
        for (int kk = 0; kk < 16; ++kk) {
            float a[8], b[8];
            *(float4*)&a[0] = *(const float4*)&As[kk * 128 + ty * 8];
            *(float4*)&a[4] = *(const float4*)&As[kk * 128 + ty * 8 + 4];
            *(float4*)&b[0] = *(const float4*)&Bs[kk * 128 + tx * 8];
            *(float4*)&b[4] = *(const float4*)&Bs[kk * 128 + tx * 8 + 4];
            #pragma unroll
            for (int i = 0; i < 8; ++i)
                #pragma unroll
                for (int j = 0; j < 8; ++j) acc[i][j] += a[i] * b[j];
        }
        __syncthreads();
    }

    float bb[8];
    #pragma unroll
    for (int j = 0; j < 8; ++j) {
        int c = col0 + tx * 8 + j;
        bb[j] = (c < DE) ? bias[c] : 0.0f;
    }
    #pragma unroll
    for (int i = 0; i < 8; ++i) {
        int r = row0 + ty * 8 + i;
        if (r < NN) {
            #pragma unroll
            for (int jp = 0; jp < 4; ++jp) {
                int c = col0 + tx * 8 + jp * 2;
                if (c < DE) {   // c even, DE even -> pair in-bounds
                    __hip_bfloat162 pv;
                    pv.x = __float2bfloat16(acc[i][jp * 2 + 0] + bb[jp * 2 + 0]);
                    pv.y = __float2bfloat16(acc[i][jp * 2 + 1] + bb[jp * 2 + 1]);
                    *(__hip_bfloat162*)&C[(size_t)r * DE + c] = pv;
                }
            }
        }
    }
}

// ---------------- one wave per edge: out[tgt] += prop[src,e,:] * gating[pos,:]
__global__ __launch_bounds__(256) void edge_kernel(const int* __restrict__ edges,
                                                   const int* __restrict__ pos_lists,
                                                   const __hip_bfloat16* __restrict__ prop,
                                                   const float* __restrict__ gating,
                                                   float* __restrict__ out,
                                                   float* __restrict__ bincount) {
    int wid = blockIdx.x * 4 + (threadIdx.x >> 6);
    if (wid >= ET * MM) return;
    int lane = threadIdx.x & 63;
    int e = wid / MM;                   // edge type
    int src = edges[2 * wid];
    int tgt = edges[2 * wid + 1];
    int pos = pos_lists[wid];
    const __hip_bfloat16* pr = prop + (size_t)src * DE + e * DD;
    const float* gr = gating + pos * DD;
    float* orow = out + (size_t)tgt * DD;
    for (int d = lane; d < DD; d += 64) {
        float v = __bfloat162float(pr[d]) * gr[d];
        atomicAdd(&orow[d], v);
    }
    if (lane == 0) atomicAdd(&bincount[tgt], 1.0f);
}

// ---------------- out /= (bincount==0 ? 1 : bincount) + 1e-8
__global__ void divide_kernel(float* __restrict__ out, const float* __restrict__ bincount) {
    size_t i = (size_t)blockIdx.x * blockDim.x + threadIdx.x;
    if (i >= (size_t)NN * DD) return;
    int n = (int)(i / DD);
    float c = bincount[n];
    float div = (c == 0.0f ? 1.0f : c) + 1e-8f;
    out[i] = out[i] / div;
}

extern "C" void kernel_launch(void* const* d_in, const int* in_sizes, int n_in,
                              void* d_out, int out_size, void* d_ws, size_t ws_size,
                              hipStream_t stream) {
    const float* node_states = (const float*)d_in[0];
    const int*   edges       = (const int*)d_in[1];
    const int*   pos_lists   = (const int*)d_in[2];
    const float* W_transform = (const float*)d_in[3];
    const float* b_transform = (const float*)d_in[4];
    const float* W_pos       = (const float*)d_in[5];
    const float* b_pos       = (const float*)d_in[6];
    float* out = (float*)d_out;

    // workspace layout
    float* gating   = (float*)d_ws;                  // 512*202 fp32   = 413,696 B
    float* bincount = gating + NPOS * DD;            // 100000 fp32    = 400,000 B
    __hip_bfloat16* prop = (__hip_bfloat16*)(bincount + NN); // 100000*1212 bf16 = 242.4 MB

    hipMemsetAsync(d_out, 0, (size_t)NN * DD * sizeof(float), stream);
    hipMemsetAsync(bincount, 0, NN * sizeof(float), stream);

    gating_kernel<<<NPOS, 256, 0, stream>>>(W_pos, b_pos, gating);

    dim3 g2((DE + 127) / 128, (NN + 127) / 128);
    gemm_kernel<<<g2, 256, 0, stream>>>(node_states, W_transform, b_transform, prop);

    edge_kernel<<<(ET * MM) / 4, 256, 0, stream>>>(edges, pos_lists, prop, gating, out, bincount);

    divide_kernel<<<(int)(((size_t)NN * DD + 255) / 256), 256, 0, stream>>>(out, bincount);
}